// Round 8
// baseline (1471.159 us; speedup 1.0000x reference)
//
#include <hip/hip_runtime.h>
#include <math.h>

// SPNet: GCN(x@Wgo), GCN(x@Wgt) -> masked attention -> encoder -> MLP heads.
// CSR-by-dst build (counts -> scan -> scatter), then all segment ops are
// deterministic per-node pulls. edge_index arrives as int32 (JAX x64 off);
// a device-side sniff also tolerates true int64 (reads low words).

__device__ __forceinline__ float lrelu(float v){ return v >= 0.f ? v : 0.2f*v; }

__device__ __forceinline__ int edge_at(const int* __restrict__ ei, int w64, size_t idx){
  return w64 ? ei[2*idx] : ei[idx];     // int64 little-endian: low word at 2*idx
}

// ----------------------------- graph build --------------------------------
__global__ void k_sniff(const int* __restrict__ ei, int* __restrict__ flag, int m){
  __shared__ int s;
  if(threadIdx.x==0) s = 0;
  __syncthreads();
  int acc = 0;
  for(int i=threadIdx.x; i<m; i+=blockDim.x) acc |= ei[2*i+1];
  atomicOr(&s, acc);
  __syncthreads();
  if(threadIdx.x==0) flag[0] = (s==0) ? 1 : 0;   // all odd words zero -> int64
}

__global__ void k_zero(int* __restrict__ p, int n){
  int i = blockIdx.x*blockDim.x + threadIdx.x;
  if(i<n) p[i]=0;
}

__global__ void k_count(const int* __restrict__ ei, const int* __restrict__ flag,
                        int* __restrict__ cnt, int E, int n){
  int e = blockIdx.x*blockDim.x + threadIdx.x;
  if(e<E){
    int d = edge_at(ei, flag[0], (size_t)E + e);
    d = min(max(d,0), n-1);                      // insurance: no OOB write
    atomicAdd(&cnt[d],1);
  }
}

__global__ void k_nodeprep(const int* __restrict__ cnt, const int* __restrict__ t,
                           float* __restrict__ dinv, float* __restrict__ tmask, int n){
  int i = blockIdx.x*blockDim.x + threadIdx.x;
  if(i<n){
    dinv[i] = rsqrtf((float)(cnt[i]+1));   // deg = in-degree + self-loop >= 1
    tmask[i] = (t[i] > 0) ? 1.f : 0.f;
  }
}

// block scans 2048 elems (256 thr x 8); writes block-local exclusive + partial
__global__ void k_scan1(const int* __restrict__ cnt, int* __restrict__ offs,
                        int* __restrict__ partials, int n){
  __shared__ int s[256];
  int tid = threadIdx.x;
  int base = blockIdx.x*2048 + tid*8;
  int v[8]; int sum=0;
  #pragma unroll
  for(int j=0;j<8;j++){ int idx=base+j; v[j] = (idx<n)? cnt[idx] : 0; sum += v[j]; }
  s[tid]=sum; __syncthreads();
  for(int off=1;off<256;off<<=1){
    int tv = (tid>=off)? s[tid-off] : 0;
    __syncthreads();
    s[tid] += tv;
    __syncthreads();
  }
  if(tid==255) partials[blockIdx.x] = s[255];
  int run = s[tid]-sum;
  #pragma unroll
  for(int j=0;j<8;j++){ int idx=base+j; if(idx<n) offs[idx]=run; run += v[j]; }
}

__global__ void k_scan2(int* __restrict__ partials, int nb){
  int lane = threadIdx.x;
  int v = (lane<nb)? partials[lane] : 0;
  int inc = v;
  for(int off=1;off<64;off<<=1){ int t2 = __shfl_up(inc,off,64); if(lane>=off) inc += t2; }
  if(lane<nb) partials[lane] = inc - v;     // exclusive
}

__global__ void k_scan3(int* __restrict__ offs, const int* __restrict__ partials,
                        int* __restrict__ cursor, int n){
  int i = blockIdx.x*blockDim.x + threadIdx.x;
  if(i<n){ int o = offs[i] + partials[i>>11]; offs[i]=o; cursor[i]=o; }
}

__global__ void k_scatter(const int* __restrict__ ei, const int* __restrict__ flag,
                          int* __restrict__ cursor, int* __restrict__ csr, int E, int n){
  int e = blockIdx.x*blockDim.x + threadIdx.x;
  if(e<E){
    int w64 = flag[0];
    int s = edge_at(ei, w64, (size_t)e);
    int d = edge_at(ei, w64, (size_t)E + e);
    s = min(max(s,0), n-1);
    d = min(max(d,0), n-1);
    int pos = atomicAdd(&cursor[d], 1);
    csr[pos] = s;
  }
}

// --------------------- transform: g = dinv * (x @ [Wgo|Wgt]) ---------------
// lanes = rows; x row in 128 VGPRs; W via wave-uniform scalar loads.
__global__ __launch_bounds__(256) void k_transform(const float* __restrict__ x,
    const float* __restrict__ Wgo, const float* __restrict__ Wgt,
    const float* __restrict__ dinv, float* __restrict__ g, int n){
  int wv = __builtin_amdgcn_readfirstlane((int)threadIdx.x >> 6);
  int lane = threadIdx.x & 63;
  int row = blockIdx.x*256 + wv*64 + lane;
  bool ok = row < n;
  int rowc = ok ? row : (n-1);
  const float4* xp = reinterpret_cast<const float4*>(x) + (size_t)rowc*32;
  float xr[128];
  #pragma unroll
  for(int q=0;q<32;q++){
    float4 t4 = xp[q];
    xr[4*q]=t4.x; xr[4*q+1]=t4.y; xr[4*q+2]=t4.z; xr[4*q+3]=t4.w;
  }
  float dv = dinv[rowc];
  float* grow = g + (size_t)rowc*128;
  #pragma unroll 1
  for(int c=0;c<64;c++){
    float a0=0.f,a1=0.f,a2=0.f,a3=0.f;
    #pragma unroll
    for(int k=0;k<128;k+=4){
      a0 += xr[k+0]*Wgo[(k+0)*64+c];
      a1 += xr[k+1]*Wgo[(k+1)*64+c];
      a2 += xr[k+2]*Wgo[(k+2)*64+c];
      a3 += xr[k+3]*Wgo[(k+3)*64+c];
    }
    if(ok) grow[c] = dv*((a0+a1)+(a2+a3));
  }
  #pragma unroll 1
  for(int c=0;c<64;c++){
    float a0=0.f,a1=0.f,a2=0.f,a3=0.f;
    #pragma unroll
    for(int k=0;k<128;k+=4){
      a0 += xr[k+0]*Wgt[(k+0)*64+c];
      a1 += xr[k+1]*Wgt[(k+1)*64+c];
      a2 += xr[k+2]*Wgt[(k+2)*64+c];
      a3 += xr[k+3]*Wgt[(k+3)*64+c];
    }
    if(ok) grow[64+c] = dv*((a0+a1)+(a2+a3));
  }
}

// ---------------- GCN pull + bias/relu + attention scores ------------------
// one wave per node; lane handles features (2*lane, 2*lane+1) of the 128.
__global__ __launch_bounds__(256) void k_gcn(const float* __restrict__ g,
    const int* __restrict__ offs, const int* __restrict__ cnt, const int* __restrict__ csr,
    const float* __restrict__ dinv, const float* __restrict__ bgo, const float* __restrict__ bgt,
    const float* __restrict__ asrc, const float* __restrict__ adst,
    float* __restrict__ r, float* __restrict__ ssc, float* __restrict__ dsc, int n){
  int wv = __builtin_amdgcn_readfirstlane((int)threadIdx.x >> 6);
  int lane = threadIdx.x & 63;
  int node = blockIdx.x*4 + wv;
  if(node>=n) return;
  const float2* gt = reinterpret_cast<const float2*>(g);
  int off = offs[node];
  int dc  = cnt[node];
  float2 acc = gt[(size_t)node*64 + lane];      // self loop
  for(int i=0;i<dc;i++){
    int u = csr[off+i];                         // wave-uniform -> scalar load
    float2 gv = gt[(size_t)u*64 + lane];
    acc.x += gv.x; acc.y += gv.y;
  }
  float dv = dinv[node];
  int f0 = 2*lane, f1 = f0+1;
  float b0 = (f0<64)? bgo[f0] : bgt[f0-64];
  float b1 = (f1<64)? bgo[f1] : bgt[f1-64];
  float r0 = dv*acc.x + b0; r0 = r0>0.f? r0 : 0.f;
  float r1 = dv*acc.y + b1; r1 = r1>0.f? r1 : 0.f;
  float2 st; st.x=r0; st.y=r1;
  reinterpret_cast<float2*>(r)[(size_t)node*64 + lane] = st;
  float ps = r0*asrc[f0] + r1*asrc[f1];
  float pd = r0*adst[f0] + r1*adst[f1];
  #pragma unroll
  for(int m=32;m>=1;m>>=1){ ps += __shfl_xor(ps,m,64); pd += __shfl_xor(pd,m,64); }
  if(lane==0){ ssc[node]=ps; dsc[node]=pd; }
}

// ----------------------- masked attention pull -----------------------------
// wave per node; pass1 lane-parallel max over treated in-edges; pass2 per-edge
// exp + gather of r_t rows (lane = feature).
__global__ __launch_bounds__(256) void k_attn(const float* __restrict__ r,
    const int* __restrict__ offs, const int* __restrict__ cnt, const int* __restrict__ csr,
    const float* __restrict__ tmask, const float* __restrict__ ssc, const float* __restrict__ dsc,
    float* __restrict__ h, int n){
  int wv = __builtin_amdgcn_readfirstlane((int)threadIdx.x >> 6);
  int lane = threadIdx.x & 63;
  int node = blockIdx.x*4 + wv;
  if(node>=n) return;
  int off = offs[node];
  int dc  = cnt[node];
  float dscv = dsc[node];
  float lmax = -3.4e38f;
  for(int i=lane;i<dc;i+=64){
    int u = csr[off+i];
    if(tmask[u] > 0.f){
      float e = lrelu(ssc[u] + dscv);
      lmax = fmaxf(lmax, e);
    }
  }
  #pragma unroll
  for(int m=32;m>=1;m>>=1) lmax = fmaxf(lmax, __shfl_xor(lmax,m,64));
  float denom = 0.f, num = 0.f;
  if(lmax > -3.0e38f){            // at least one treated in-edge
    for(int i=0;i<dc;i++){
      int u = csr[off+i];         // wave-uniform
      float tm = tmask[u];        // wave-uniform
      if(tm > 0.f){
        float e = lrelu(ssc[u] + dscv);
        float w = __expf(e - lmax);
        denom += w;
        num += w * r[(size_t)u*128 + 64 + lane];   // r_t[u][lane]
      }
    }
  }
  h[(size_t)node*64 + lane] = num/(denom + 1e-16f);
}

// ------------------------------ heads --------------------------------------
// lanes = nodes; per-layer activations live in this thread's own LDS column;
// weights are wave-uniform scalar loads. block = 128 threads.
__global__ __launch_bounds__(128) void k_heads(
    const float* __restrict__ r, const float* __restrict__ h, const int* __restrict__ t,
    const float* __restrict__ Wenc, const float* __restrict__ benc,
    const float* __restrict__ dw1, const float* __restrict__ db1,
    const float* __restrict__ dw2, const float* __restrict__ db2,
    const float* __restrict__ dw3, const float* __restrict__ db3,
    const float* __restrict__ p1w1, const float* __restrict__ p1b1,
    const float* __restrict__ p1w2, const float* __restrict__ p1b2,
    const float* __restrict__ p1w3, const float* __restrict__ p1b3,
    const float* __restrict__ p0w1, const float* __restrict__ p0b1,
    const float* __restrict__ p0w2, const float* __restrict__ p0b2,
    const float* __restrict__ p0w3, const float* __restrict__ p0b3,
    float* __restrict__ out, int n){
  __shared__ float buf[64][130];
  int tid = threadIdx.x;
  int vbase = blockIdx.x*128;
  int v = vbase + tid;
  bool act = v < n;

  auto stage = [&](const float* __restrict__ src, int stride){
    __syncthreads();
    #pragma unroll 1
    for(int jj=0;jj<64;jj++){           // 8192 elems, coalesced in 64-chunks
      int e = jj*128 + tid;
      int nl = e>>6, u = e&63;
      int node = vbase + nl;
      buf[u][nl] = (node<n)? src[(size_t)node*stride + u] : 0.f;
    }
    __syncthreads();
  };

  float acc[64];
  auto mlayer = [&](const float* __restrict__ w, const float* __restrict__ b){
    #pragma unroll
    for(int i=0;i<64;i++) acc[i]=b[i];
    #pragma unroll 1
    for(int k=0;k<64;k++){
      float ink = buf[k][tid];
      #pragma unroll
      for(int i=0;i<64;i++) acc[i] += ink*w[k*64+i];
    }
    #pragma unroll
    for(int i=0;i<64;i++) buf[i][tid] = lrelu(acc[i]);   // own column: no sync
  };
  auto last = [&](const float* __restrict__ w3, const float* __restrict__ b3)->float{
    float o = b3[0];
    #pragma unroll 1
    for(int k=0;k<64;k++) o += buf[k][tid]*w3[k];
    return o;
  };

  // discriminator on r_t
  stage(r + 64, 128);
  mlayer(dw1, db1);
  mlayer(dw2, db2);
  float od = last(dw3, db3);
  if(act) out[v] = 1.f/(1.f + __expf(-od));

  // encoder: reps = [r_o | h] @ Wenc + benc  (no activation)
  stage(r, 128);
  #pragma unroll
  for(int i=0;i<64;i++) acc[i]=benc[i];
  #pragma unroll 1
  for(int k=0;k<64;k++){
    float ink = buf[k][tid];
    #pragma unroll
    for(int i=0;i<64;i++) acc[i] += ink*Wenc[k*64+i];
  }
  stage(h, 64);
  #pragma unroll 1
  for(int k=0;k<64;k++){
    float ink = buf[k][tid];
    #pragma unroll
    for(int i=0;i<64;i++) acc[i] += ink*Wenc[(64+k)*64+i];
  }
  float reps[64];
  #pragma unroll
  for(int i=0;i<64;i++){ reps[i]=acc[i]; buf[i][tid]=acc[i]; }
  if(act){
    float* rp = out + (size_t)2*n + (size_t)v*64;
    #pragma unroll
    for(int i=0;i<64;i++) rp[i] = reps[i];
  }

  // predictor 1
  mlayer(p1w1, p1b1);
  mlayer(p1w2, p1b2);
  float o1 = last(p1w3, p1b3);
  // restore reps (own column)
  #pragma unroll
  for(int i=0;i<64;i++) buf[i][tid] = reps[i];
  // predictor 0
  mlayer(p0w1, p0b1);
  mlayer(p0w2, p0b2);
  float o0 = last(p0w3, p0b3);
  if(act) out[n + v] = (t[v] > 0) ? o1 : o0;
}

// ------------------------------ launch -------------------------------------
extern "C" void kernel_launch(void* const* d_in, const int* in_sizes, int n_in,
                              void* d_out, int out_size, void* d_ws, size_t ws_size,
                              hipStream_t stream){
  const float* x   = (const float*)d_in[0];
  const int*   t   = (const int*)d_in[1];
  const int*   ei  = (const int*)d_in[3];   // int32 (JAX x64 off); sniff handles int64
  const float* Wgo = (const float*)d_in[4];  const float* bgo = (const float*)d_in[5];
  const float* Wgt = (const float*)d_in[6];  const float* bgt = (const float*)d_in[7];
  const float* asrc= (const float*)d_in[8];  const float* adst= (const float*)d_in[9];
  const float* Wenc= (const float*)d_in[10]; const float* benc= (const float*)d_in[11];
  const float* dw1 = (const float*)d_in[12]; const float* db1 = (const float*)d_in[13];
  const float* dw2 = (const float*)d_in[14]; const float* db2 = (const float*)d_in[15];
  const float* dw3 = (const float*)d_in[16]; const float* db3 = (const float*)d_in[17];
  const float* p1w1= (const float*)d_in[18]; const float* p1b1= (const float*)d_in[19];
  const float* p1w2= (const float*)d_in[20]; const float* p1b2= (const float*)d_in[21];
  const float* p1w3= (const float*)d_in[22]; const float* p1b3= (const float*)d_in[23];
  const float* p0w1= (const float*)d_in[24]; const float* p0b1= (const float*)d_in[25];
  const float* p0w2= (const float*)d_in[26]; const float* p0b2= (const float*)d_in[27];
  const float* p0w3= (const float*)d_in[28]; const float* p0b3= (const float*)d_in[29];
  float* out = (float*)d_out;

  int N = in_sizes[0]/128;
  int E = in_sizes[3]/2;

  char* wp = (char*)d_ws;
  auto alloc = [&](size_t bytes)->void*{
    void* p = (void*)wp; wp += (bytes + 255) & ~(size_t)255; return p;
  };
  float* g     = (float*)alloc((size_t)N*128*sizeof(float));
  float* r     = (float*)alloc((size_t)N*128*sizeof(float));
  int*   csr   = (int*)  alloc((size_t)E*sizeof(int));
  int*   offs  = (int*)  alloc((size_t)N*sizeof(int));
  int*   cursor= (int*)  alloc((size_t)N*sizeof(int));
  int*   cnt   = (int*)  alloc((size_t)N*sizeof(int));
  float* dinv  = (float*)alloc((size_t)N*sizeof(float));
  float* tmask = (float*)alloc((size_t)N*sizeof(float));
  float* ssc   = (float*)alloc((size_t)N*sizeof(float));
  float* dsc   = (float*)alloc((size_t)N*sizeof(float));
  int*   parts = (int*)  alloc(4096);
  int*   flag  = (int*)  alloc(256);
  float* h     = g;                  // g is dead after k_gcn; reuse for h

  int nbN  = (N+255)/256;
  int nbE  = (E+255)/256;
  int nbSc = (N+2047)/2048;

  k_sniff   <<<1,   256, 0, stream>>>(ei, flag, 1024);
  k_zero    <<<nbN, 256, 0, stream>>>(cnt, N);
  k_count   <<<nbE, 256, 0, stream>>>(ei, flag, cnt, E, N);
  k_nodeprep<<<nbN, 256, 0, stream>>>(cnt, t, dinv, tmask, N);
  k_scan1   <<<nbSc,256, 0, stream>>>(cnt, offs, parts, N);
  k_scan2   <<<1,   64,  0, stream>>>(parts, nbSc);
  k_scan3   <<<nbN, 256, 0, stream>>>(offs, parts, cursor, N);
  k_scatter <<<nbE, 256, 0, stream>>>(ei, flag, cursor, csr, E, N);
  k_transform<<<(N+255)/256, 256, 0, stream>>>(x, Wgo, Wgt, dinv, g, N);
  k_gcn     <<<(N+3)/4, 256, 0, stream>>>(g, offs, cnt, csr, dinv, bgo, bgt,
                                          asrc, adst, r, ssc, dsc, N);
  k_attn    <<<(N+3)/4, 256, 0, stream>>>(r, offs, cnt, csr, tmask, ssc, dsc, h, N);
  k_heads   <<<(N+127)/128, 128, 0, stream>>>(r, h, t,
              Wenc, benc, dw1, db1, dw2, db2, dw3, db3,
              p1w1, p1b1, p1w2, p1b2, p1w3, p1b3,
              p0w1, p0b1, p0w2, p0b2, p0w3, p0b3, out, N);
}

// Round 9
// 1239.299 us; speedup vs baseline: 1.1871x; 1.1871x over previous
//
#include <hip/hip_runtime.h>
#include <math.h>

// SPNet: GCN(x@Wgo), GCN(x@Wgt) -> masked attention -> encoder -> MLP heads.
// CSR-by-dst build (counts -> scan -> scatter), then all segment ops are
// deterministic per-node pulls. edge_index arrives as int32 (JAX x64 off);
// a device-side sniff also tolerates true int64 (reads low words).
// R8 fix: k_heads restructured (thread = node x 16-output chunk) to kill
// scratch spilling (was 382 MB writes, VALUBusy 6.7%, 790 us).

__device__ __forceinline__ float lrelu(float v){ return v >= 0.f ? v : 0.2f*v; }

__device__ __forceinline__ int edge_at(const int* __restrict__ ei, int w64, size_t idx){
  return w64 ? ei[2*idx] : ei[idx];     // int64 little-endian: low word at 2*idx
}

// ----------------------------- graph build --------------------------------
__global__ void k_sniff(const int* __restrict__ ei, int* __restrict__ flag, int m){
  __shared__ int s;
  if(threadIdx.x==0) s = 0;
  __syncthreads();
  int acc = 0;
  for(int i=threadIdx.x; i<m; i+=blockDim.x) acc |= ei[2*i+1];
  atomicOr(&s, acc);
  __syncthreads();
  if(threadIdx.x==0) flag[0] = (s==0) ? 1 : 0;   // all odd words zero -> int64
}

__global__ void k_zero(int* __restrict__ p, int n){
  int i = blockIdx.x*blockDim.x + threadIdx.x;
  if(i<n) p[i]=0;
}

__global__ void k_count(const int* __restrict__ ei, const int* __restrict__ flag,
                        int* __restrict__ cnt, int E, int n){
  int e = blockIdx.x*blockDim.x + threadIdx.x;
  if(e<E){
    int d = edge_at(ei, flag[0], (size_t)E + e);
    d = min(max(d,0), n-1);                      // insurance: no OOB write
    atomicAdd(&cnt[d],1);
  }
}

__global__ void k_nodeprep(const int* __restrict__ cnt, const int* __restrict__ t,
                           float* __restrict__ dinv, float* __restrict__ tmask, int n){
  int i = blockIdx.x*blockDim.x + threadIdx.x;
  if(i<n){
    dinv[i] = rsqrtf((float)(cnt[i]+1));   // deg = in-degree + self-loop >= 1
    tmask[i] = (t[i] > 0) ? 1.f : 0.f;
  }
}

// block scans 2048 elems (256 thr x 8); writes block-local exclusive + partial
__global__ void k_scan1(const int* __restrict__ cnt, int* __restrict__ offs,
                        int* __restrict__ partials, int n){
  __shared__ int s[256];
  int tid = threadIdx.x;
  int base = blockIdx.x*2048 + tid*8;
  int v[8]; int sum=0;
  #pragma unroll
  for(int j=0;j<8;j++){ int idx=base+j; v[j] = (idx<n)? cnt[idx] : 0; sum += v[j]; }
  s[tid]=sum; __syncthreads();
  for(int off=1;off<256;off<<=1){
    int tv = (tid>=off)? s[tid-off] : 0;
    __syncthreads();
    s[tid] += tv;
    __syncthreads();
  }
  if(tid==255) partials[blockIdx.x] = s[255];
  int run = s[tid]-sum;
  #pragma unroll
  for(int j=0;j<8;j++){ int idx=base+j; if(idx<n) offs[idx]=run; run += v[j]; }
}

__global__ void k_scan2(int* __restrict__ partials, int nb){
  int lane = threadIdx.x;
  int v = (lane<nb)? partials[lane] : 0;
  int inc = v;
  for(int off=1;off<64;off<<=1){ int t2 = __shfl_up(inc,off,64); if(lane>=off) inc += t2; }
  if(lane<nb) partials[lane] = inc - v;     // exclusive
}

__global__ void k_scan3(int* __restrict__ offs, const int* __restrict__ partials,
                        int* __restrict__ cursor, int n){
  int i = blockIdx.x*blockDim.x + threadIdx.x;
  if(i<n){ int o = offs[i] + partials[i>>11]; offs[i]=o; cursor[i]=o; }
}

__global__ void k_scatter(const int* __restrict__ ei, const int* __restrict__ flag,
                          int* __restrict__ cursor, int* __restrict__ csr, int E, int n){
  int e = blockIdx.x*blockDim.x + threadIdx.x;
  if(e<E){
    int w64 = flag[0];
    int s = edge_at(ei, w64, (size_t)e);
    int d = edge_at(ei, w64, (size_t)E + e);
    s = min(max(s,0), n-1);
    d = min(max(d,0), n-1);
    int pos = atomicAdd(&cursor[d], 1);
    csr[pos] = s;
  }
}

// --------------------- transform: g = dinv * (x @ [Wgo|Wgt]) ---------------
// lanes = rows; x row in 128 VGPRs; W via wave-uniform scalar loads.
__global__ __launch_bounds__(256) void k_transform(const float* __restrict__ x,
    const float* __restrict__ Wgo, const float* __restrict__ Wgt,
    const float* __restrict__ dinv, float* __restrict__ g, int n){
  int wv = __builtin_amdgcn_readfirstlane((int)threadIdx.x >> 6);
  int lane = threadIdx.x & 63;
  int row = blockIdx.x*256 + wv*64 + lane;
  bool ok = row < n;
  int rowc = ok ? row : (n-1);
  const float4* xp = reinterpret_cast<const float4*>(x) + (size_t)rowc*32;
  float xr[128];
  #pragma unroll
  for(int q=0;q<32;q++){
    float4 t4 = xp[q];
    xr[4*q]=t4.x; xr[4*q+1]=t4.y; xr[4*q+2]=t4.z; xr[4*q+3]=t4.w;
  }
  float dv = dinv[rowc];
  float* grow = g + (size_t)rowc*128;
  #pragma unroll 1
  for(int c=0;c<64;c++){
    float a0=0.f,a1=0.f,a2=0.f,a3=0.f;
    #pragma unroll
    for(int k=0;k<128;k+=4){
      a0 += xr[k+0]*Wgo[(k+0)*64+c];
      a1 += xr[k+1]*Wgo[(k+1)*64+c];
      a2 += xr[k+2]*Wgo[(k+2)*64+c];
      a3 += xr[k+3]*Wgo[(k+3)*64+c];
    }
    if(ok) grow[c] = dv*((a0+a1)+(a2+a3));
  }
  #pragma unroll 1
  for(int c=0;c<64;c++){
    float a0=0.f,a1=0.f,a2=0.f,a3=0.f;
    #pragma unroll
    for(int k=0;k<128;k+=4){
      a0 += xr[k+0]*Wgt[(k+0)*64+c];
      a1 += xr[k+1]*Wgt[(k+1)*64+c];
      a2 += xr[k+2]*Wgt[(k+2)*64+c];
      a3 += xr[k+3]*Wgt[(k+3)*64+c];
    }
    if(ok) grow[64+c] = dv*((a0+a1)+(a2+a3));
  }
}

// ---------------- GCN pull + bias/relu + attention scores ------------------
// one wave per node; lane handles features (2*lane, 2*lane+1) of the 128.
__global__ __launch_bounds__(256) void k_gcn(const float* __restrict__ g,
    const int* __restrict__ offs, const int* __restrict__ cnt, const int* __restrict__ csr,
    const float* __restrict__ dinv, const float* __restrict__ bgo, const float* __restrict__ bgt,
    const float* __restrict__ asrc, const float* __restrict__ adst,
    float* __restrict__ r, float* __restrict__ ssc, float* __restrict__ dsc, int n){
  int wv = __builtin_amdgcn_readfirstlane((int)threadIdx.x >> 6);
  int lane = threadIdx.x & 63;
  int node = blockIdx.x*4 + wv;
  if(node>=n) return;
  const float2* gt = reinterpret_cast<const float2*>(g);
  int off = offs[node];
  int dc  = cnt[node];
  float2 acc = gt[(size_t)node*64 + lane];      // self loop
  for(int i=0;i<dc;i++){
    int u = csr[off+i];                         // wave-uniform -> scalar load
    float2 gv = gt[(size_t)u*64 + lane];
    acc.x += gv.x; acc.y += gv.y;
  }
  float dv = dinv[node];
  int f0 = 2*lane, f1 = f0+1;
  float b0 = (f0<64)? bgo[f0] : bgt[f0-64];
  float b1 = (f1<64)? bgo[f1] : bgt[f1-64];
  float r0 = dv*acc.x + b0; r0 = r0>0.f? r0 : 0.f;
  float r1 = dv*acc.y + b1; r1 = r1>0.f? r1 : 0.f;
  float2 st; st.x=r0; st.y=r1;
  reinterpret_cast<float2*>(r)[(size_t)node*64 + lane] = st;
  float ps = r0*asrc[f0] + r1*asrc[f1];
  float pd = r0*adst[f0] + r1*adst[f1];
  #pragma unroll
  for(int m=32;m>=1;m>>=1){ ps += __shfl_xor(ps,m,64); pd += __shfl_xor(pd,m,64); }
  if(lane==0){ ssc[node]=ps; dsc[node]=pd; }
}

// ----------------------- masked attention pull -----------------------------
__global__ __launch_bounds__(256) void k_attn(const float* __restrict__ r,
    const int* __restrict__ offs, const int* __restrict__ cnt, const int* __restrict__ csr,
    const float* __restrict__ tmask, const float* __restrict__ ssc, const float* __restrict__ dsc,
    float* __restrict__ h, int n){
  int wv = __builtin_amdgcn_readfirstlane((int)threadIdx.x >> 6);
  int lane = threadIdx.x & 63;
  int node = blockIdx.x*4 + wv;
  if(node>=n) return;
  int off = offs[node];
  int dc  = cnt[node];
  float dscv = dsc[node];
  float lmax = -3.4e38f;
  for(int i=lane;i<dc;i+=64){
    int u = csr[off+i];
    if(tmask[u] > 0.f){
      float e = lrelu(ssc[u] + dscv);
      lmax = fmaxf(lmax, e);
    }
  }
  #pragma unroll
  for(int m=32;m>=1;m>>=1) lmax = fmaxf(lmax, __shfl_xor(lmax,m,64));
  float denom = 0.f, num = 0.f;
  if(lmax > -3.0e38f){            // at least one treated in-edge
    for(int i=0;i<dc;i++){
      int u = csr[off+i];         // wave-uniform
      float tm = tmask[u];        // wave-uniform
      if(tm > 0.f){
        float e = lrelu(ssc[u] + dscv);
        float w = __expf(e - lmax);
        denom += w;
        num += w * r[(size_t)u*128 + 64 + lane];   // r_t[u][lane]
      }
    }
  }
  h[(size_t)node*64 + lane] = num/(denom + 1e-16f);
}

// ------------------------------ heads --------------------------------------
// R8: block = 256 thr = 64 nodes x 4 output-chunks. Thread owns acc[16] only
// (statically indexed -> VGPRs, no scratch). Activations ping-pong A<->B in
// LDS ([64][65] pad -> conflict-free). Weight loads wave-uniform -> s_load.
__global__ __launch_bounds__(256) void k_heads(
    const float* __restrict__ r, const float* __restrict__ h, const int* __restrict__ t,
    const float* __restrict__ Wenc, const float* __restrict__ benc,
    const float* __restrict__ dw1, const float* __restrict__ db1,
    const float* __restrict__ dw2, const float* __restrict__ db2,
    const float* __restrict__ dw3, const float* __restrict__ db3,
    const float* __restrict__ p1w1, const float* __restrict__ p1b1,
    const float* __restrict__ p1w2, const float* __restrict__ p1b2,
    const float* __restrict__ p1w3, const float* __restrict__ p1b3,
    const float* __restrict__ p0w1, const float* __restrict__ p0b1,
    const float* __restrict__ p0w2, const float* __restrict__ p0b2,
    const float* __restrict__ p0w3, const float* __restrict__ p0b3,
    float* __restrict__ out, int nTot){
  __shared__ float A[64][65];
  __shared__ float B[64][65];
  int tid = threadIdx.x;
  int n   = tid & 63;            // node within block
  int c   = tid >> 6;            // output chunk (wave-uniform)
  int node = blockIdx.x*64 + n;
  bool act = node < nTot;

  // stage 64 nodes x 64 feats: dst[f][nn] = src[gn*stride + f]
  auto stage = [&](float (*dst)[65], const float* __restrict__ src, int stride){
    __syncthreads();
    #pragma unroll 1
    for(int it=0; it<16; it++){
      int e  = it*256 + tid;
      int nn = e >> 6, f = e & 63;
      int gn = blockIdx.x*64 + nn;
      dst[f][nn] = (gn < nTot) ? src[(size_t)gn*stride + f] : 0.f;
    }
    __syncthreads();
  };

  // layer: outb = lrelu?(in @ w + b), chunk c of outputs per thread
  auto mlayer = [&](float (*in)[65], float (*outb)[65],
                    const float* __restrict__ w, const float* __restrict__ b, bool relu){
    float acc[16];
    #pragma unroll
    for(int i=0;i<16;i++) acc[i] = b[c*16+i];
    #pragma unroll 1
    for(int k=0;k<64;k++){
      float ink = in[k][n];
      #pragma unroll
      for(int i=0;i<16;i++) acc[i] += ink * w[k*64 + c*16 + i];
    }
    #pragma unroll
    for(int i=0;i<16;i++) outb[c*16+i][n] = relu ? lrelu(acc[i]) : acc[i];
    __syncthreads();
  };

  auto last = [&](float (*in)[65], const float* __restrict__ w3, float b3)->float{
    float o = b3;
    #pragma unroll 1
    for(int k=0;k<64;k++) o += in[k][n]*w3[k];
    return o;
  };

  // ---- discriminator on r_t ----
  stage(A, r + 64, 128);
  mlayer(A, B, dw1, db1, true);
  mlayer(B, A, dw2, db2, true);
  float od = last(A, dw3, db3[0]);
  if(act && c==0) out[node] = 1.f/(1.f + __expf(-od));

  // ---- encoder: reps = [r_o | h] @ Wenc + benc ----
  float rep[16];
  #pragma unroll
  for(int i=0;i<16;i++) rep[i] = benc[c*16+i];
  stage(A, r, 128);                       // r_o
  #pragma unroll 1
  for(int k=0;k<64;k++){
    float ink = A[k][n];
    #pragma unroll
    for(int i=0;i<16;i++) rep[i] += ink * Wenc[k*64 + c*16 + i];
  }
  stage(A, h, 64);                        // h
  #pragma unroll 1
  for(int k=0;k<64;k++){
    float ink = A[k][n];
    #pragma unroll
    for(int i=0;i<16;i++) rep[i] += ink * Wenc[(64+k)*64 + c*16 + i];
  }
  __syncthreads();                        // A reads done before B write barrier below
  #pragma unroll
  for(int i=0;i<16;i++) B[c*16+i][n] = rep[i];
  __syncthreads();
  // coalesced reps -> global via B
  #pragma unroll 1
  for(int it=0; it<16; it++){
    int e  = it*256 + tid;
    int nn = e >> 6, f = e & 63;
    int gn = blockIdx.x*64 + nn;
    if(gn < nTot) out[(size_t)2*nTot + (size_t)gn*64 + f] = B[f][nn];
  }

  // ---- predictor 1 (destroys B) ----
  mlayer(B, A, p1w1, p1b1, true);
  mlayer(A, B, p1w2, p1b2, true);
  float o1 = last(B, p1w3, p1b3[0]);
  // restore reps into B from registers
  __syncthreads();
  #pragma unroll
  for(int i=0;i<16;i++) B[c*16+i][n] = rep[i];
  __syncthreads();
  // ---- predictor 0 ----
  mlayer(B, A, p0w1, p0b1, true);
  mlayer(A, B, p0w2, p0b2, true);
  float o0 = last(B, p0w3, p0b3[0]);
  if(act && c==0) out[nTot + node] = (t[node] > 0) ? o1 : o0;
}

// ------------------------------ launch -------------------------------------
extern "C" void kernel_launch(void* const* d_in, const int* in_sizes, int n_in,
                              void* d_out, int out_size, void* d_ws, size_t ws_size,
                              hipStream_t stream){
  const float* x   = (const float*)d_in[0];
  const int*   t   = (const int*)d_in[1];
  const int*   ei  = (const int*)d_in[3];   // int32 (JAX x64 off); sniff handles int64
  const float* Wgo = (const float*)d_in[4];  const float* bgo = (const float*)d_in[5];
  const float* Wgt = (const float*)d_in[6];  const float* bgt = (const float*)d_in[7];
  const float* asrc= (const float*)d_in[8];  const float* adst= (const float*)d_in[9];
  const float* Wenc= (const float*)d_in[10]; const float* benc= (const float*)d_in[11];
  const float* dw1 = (const float*)d_in[12]; const float* db1 = (const float*)d_in[13];
  const float* dw2 = (const float*)d_in[14]; const float* db2 = (const float*)d_in[15];
  const float* dw3 = (const float*)d_in[16]; const float* db3 = (const float*)d_in[17];
  const float* p1w1= (const float*)d_in[18]; const float* p1b1= (const float*)d_in[19];
  const float* p1w2= (const float*)d_in[20]; const float* p1b2= (const float*)d_in[21];
  const float* p1w3= (const float*)d_in[22]; const float* p1b3= (const float*)d_in[23];
  const float* p0w1= (const float*)d_in[24]; const float* p0b1= (const float*)d_in[25];
  const float* p0w2= (const float*)d_in[26]; const float* p0b2= (const float*)d_in[27];
  const float* p0w3= (const float*)d_in[28]; const float* p0b3= (const float*)d_in[29];
  float* out = (float*)d_out;

  int N = in_sizes[0]/128;
  int E = in_sizes[3]/2;

  char* wp = (char*)d_ws;
  auto alloc = [&](size_t bytes)->void*{
    void* p = (void*)wp; wp += (bytes + 255) & ~(size_t)255; return p;
  };
  float* g     = (float*)alloc((size_t)N*128*sizeof(float));
  float* r     = (float*)alloc((size_t)N*128*sizeof(float));
  int*   csr   = (int*)  alloc((size_t)E*sizeof(int));
  int*   offs  = (int*)  alloc((size_t)N*sizeof(int));
  int*   cursor= (int*)  alloc((size_t)N*sizeof(int));
  int*   cnt   = (int*)  alloc((size_t)N*sizeof(int));
  float* dinv  = (float*)alloc((size_t)N*sizeof(float));
  float* tmask = (float*)alloc((size_t)N*sizeof(float));
  float* ssc   = (float*)alloc((size_t)N*sizeof(float));
  float* dsc   = (float*)alloc((size_t)N*sizeof(float));
  int*   parts = (int*)  alloc(4096);
  int*   flag  = (int*)  alloc(256);
  float* h     = g;                  // g is dead after k_gcn; reuse for h

  int nbN  = (N+255)/256;
  int nbE  = (E+255)/256;
  int nbSc = (N+2047)/2048;

  k_sniff   <<<1,   256, 0, stream>>>(ei, flag, 1024);
  k_zero    <<<nbN, 256, 0, stream>>>(cnt, N);
  k_count   <<<nbE, 256, 0, stream>>>(ei, flag, cnt, E, N);
  k_nodeprep<<<nbN, 256, 0, stream>>>(cnt, t, dinv, tmask, N);
  k_scan1   <<<nbSc,256, 0, stream>>>(cnt, offs, parts, N);
  k_scan2   <<<1,   64,  0, stream>>>(parts, nbSc);
  k_scan3   <<<nbN, 256, 0, stream>>>(offs, parts, cursor, N);
  k_scatter <<<nbE, 256, 0, stream>>>(ei, flag, cursor, csr, E, N);
  k_transform<<<(N+255)/256, 256, 0, stream>>>(x, Wgo, Wgt, dinv, g, N);
  k_gcn     <<<(N+3)/4, 256, 0, stream>>>(g, offs, cnt, csr, dinv, bgo, bgt,
                                          asrc, adst, r, ssc, dsc, N);
  k_attn    <<<(N+3)/4, 256, 0, stream>>>(r, offs, cnt, csr, tmask, ssc, dsc, h, N);
  k_heads   <<<(N+63)/64, 256, 0, stream>>>(r, h, t,
              Wenc, benc, dw1, db1, dw2, db2, dw3, db3,
              p1w1, p1b1, p1w2, p1b2, p1w3, p1b3,
              p0w1, p0b1, p0w2, p0b2, p0w3, p0b3, out, N);
}

// Round 10
// 1047.820 us; speedup vs baseline: 1.4040x; 1.1827x over previous
//
#include <hip/hip_runtime.h>
#include <math.h>

// SPNet: GCN(x@Wgo), GCN(x@Wgt) -> masked attention -> encoder -> MLP heads.
// CSR-by-dst build (counts -> scan -> scatter), then all segment ops are
// deterministic per-node pulls. edge_index arrives as int32 (JAX x64 off);
// a device-side sniff also tolerates true int64 (reads low words).
// R8: k_heads restructured (thread = node x 16-output chunk) -> no scratch.
// R9: k_heads chunk id via readfirstlane -> weight loads become s_load
//     (were divergent vector loads: VALUBusy 12.7%, latency-bound, 531 us).

__device__ __forceinline__ float lrelu(float v){ return v >= 0.f ? v : 0.2f*v; }

__device__ __forceinline__ int edge_at(const int* __restrict__ ei, int w64, size_t idx){
  return w64 ? ei[2*idx] : ei[idx];     // int64 little-endian: low word at 2*idx
}

// ----------------------------- graph build --------------------------------
__global__ void k_sniff(const int* __restrict__ ei, int* __restrict__ flag, int m){
  __shared__ int s;
  if(threadIdx.x==0) s = 0;
  __syncthreads();
  int acc = 0;
  for(int i=threadIdx.x; i<m; i+=blockDim.x) acc |= ei[2*i+1];
  atomicOr(&s, acc);
  __syncthreads();
  if(threadIdx.x==0) flag[0] = (s==0) ? 1 : 0;   // all odd words zero -> int64
}

__global__ void k_zero(int* __restrict__ p, int n){
  int i = blockIdx.x*blockDim.x + threadIdx.x;
  if(i<n) p[i]=0;
}

__global__ void k_count(const int* __restrict__ ei, const int* __restrict__ flag,
                        int* __restrict__ cnt, int E, int n){
  int e = blockIdx.x*blockDim.x + threadIdx.x;
  if(e<E){
    int d = edge_at(ei, flag[0], (size_t)E + e);
    d = min(max(d,0), n-1);                      // insurance: no OOB write
    atomicAdd(&cnt[d],1);
  }
}

__global__ void k_nodeprep(const int* __restrict__ cnt, const int* __restrict__ t,
                           float* __restrict__ dinv, float* __restrict__ tmask, int n){
  int i = blockIdx.x*blockDim.x + threadIdx.x;
  if(i<n){
    dinv[i] = rsqrtf((float)(cnt[i]+1));   // deg = in-degree + self-loop >= 1
    tmask[i] = (t[i] > 0) ? 1.f : 0.f;
  }
}

// block scans 2048 elems (256 thr x 8); writes block-local exclusive + partial
__global__ void k_scan1(const int* __restrict__ cnt, int* __restrict__ offs,
                        int* __restrict__ partials, int n){
  __shared__ int s[256];
  int tid = threadIdx.x;
  int base = blockIdx.x*2048 + tid*8;
  int v[8]; int sum=0;
  #pragma unroll
  for(int j=0;j<8;j++){ int idx=base+j; v[j] = (idx<n)? cnt[idx] : 0; sum += v[j]; }
  s[tid]=sum; __syncthreads();
  for(int off=1;off<256;off<<=1){
    int tv = (tid>=off)? s[tid-off] : 0;
    __syncthreads();
    s[tid] += tv;
    __syncthreads();
  }
  if(tid==255) partials[blockIdx.x] = s[255];
  int run = s[tid]-sum;
  #pragma unroll
  for(int j=0;j<8;j++){ int idx=base+j; if(idx<n) offs[idx]=run; run += v[j]; }
}

__global__ void k_scan2(int* __restrict__ partials, int nb){
  int lane = threadIdx.x;
  int v = (lane<nb)? partials[lane] : 0;
  int inc = v;
  for(int off=1;off<64;off<<=1){ int t2 = __shfl_up(inc,off,64); if(lane>=off) inc += t2; }
  if(lane<nb) partials[lane] = inc - v;     // exclusive
}

__global__ void k_scan3(int* __restrict__ offs, const int* __restrict__ partials,
                        int* __restrict__ cursor, int n){
  int i = blockIdx.x*blockDim.x + threadIdx.x;
  if(i<n){ int o = offs[i] + partials[i>>11]; offs[i]=o; cursor[i]=o; }
}

__global__ void k_scatter(const int* __restrict__ ei, const int* __restrict__ flag,
                          int* __restrict__ cursor, int* __restrict__ csr, int E, int n){
  int e = blockIdx.x*blockDim.x + threadIdx.x;
  if(e<E){
    int w64 = flag[0];
    int s = edge_at(ei, w64, (size_t)e);
    int d = edge_at(ei, w64, (size_t)E + e);
    s = min(max(s,0), n-1);
    d = min(max(d,0), n-1);
    int pos = atomicAdd(&cursor[d], 1);
    csr[pos] = s;
  }
}

// --------------------- transform: g = dinv * (x @ [Wgo|Wgt]) ---------------
// lanes = rows; x row in 128 VGPRs; W via wave-uniform scalar loads.
__global__ __launch_bounds__(256) void k_transform(const float* __restrict__ x,
    const float* __restrict__ Wgo, const float* __restrict__ Wgt,
    const float* __restrict__ dinv, float* __restrict__ g, int n){
  int wv = __builtin_amdgcn_readfirstlane((int)threadIdx.x >> 6);
  int lane = threadIdx.x & 63;
  int row = blockIdx.x*256 + wv*64 + lane;
  bool ok = row < n;
  int rowc = ok ? row : (n-1);
  const float4* xp = reinterpret_cast<const float4*>(x) + (size_t)rowc*32;
  float xr[128];
  #pragma unroll
  for(int q=0;q<32;q++){
    float4 t4 = xp[q];
    xr[4*q]=t4.x; xr[4*q+1]=t4.y; xr[4*q+2]=t4.z; xr[4*q+3]=t4.w;
  }
  float dv = dinv[rowc];
  float* grow = g + (size_t)rowc*128;
  #pragma unroll 1
  for(int c=0;c<64;c++){
    float a0=0.f,a1=0.f,a2=0.f,a3=0.f;
    #pragma unroll
    for(int k=0;k<128;k+=4){
      a0 += xr[k+0]*Wgo[(k+0)*64+c];
      a1 += xr[k+1]*Wgo[(k+1)*64+c];
      a2 += xr[k+2]*Wgo[(k+2)*64+c];
      a3 += xr[k+3]*Wgo[(k+3)*64+c];
    }
    if(ok) grow[c] = dv*((a0+a1)+(a2+a3));
  }
  #pragma unroll 1
  for(int c=0;c<64;c++){
    float a0=0.f,a1=0.f,a2=0.f,a3=0.f;
    #pragma unroll
    for(int k=0;k<128;k+=4){
      a0 += xr[k+0]*Wgt[(k+0)*64+c];
      a1 += xr[k+1]*Wgt[(k+1)*64+c];
      a2 += xr[k+2]*Wgt[(k+2)*64+c];
      a3 += xr[k+3]*Wgt[(k+3)*64+c];
    }
    if(ok) grow[64+c] = dv*((a0+a1)+(a2+a3));
  }
}

// ---------------- GCN pull + bias/relu + attention scores ------------------
// one wave per node; lane handles features (2*lane, 2*lane+1) of the 128.
__global__ __launch_bounds__(256) void k_gcn(const float* __restrict__ g,
    const int* __restrict__ offs, const int* __restrict__ cnt, const int* __restrict__ csr,
    const float* __restrict__ dinv, const float* __restrict__ bgo, const float* __restrict__ bgt,
    const float* __restrict__ asrc, const float* __restrict__ adst,
    float* __restrict__ r, float* __restrict__ ssc, float* __restrict__ dsc, int n){
  int wv = __builtin_amdgcn_readfirstlane((int)threadIdx.x >> 6);
  int lane = threadIdx.x & 63;
  int node = blockIdx.x*4 + wv;
  if(node>=n) return;
  const float2* gt = reinterpret_cast<const float2*>(g);
  int off = offs[node];
  int dc  = cnt[node];
  float2 acc = gt[(size_t)node*64 + lane];      // self loop
  for(int i=0;i<dc;i++){
    int u = csr[off+i];                         // wave-uniform -> scalar load
    float2 gv = gt[(size_t)u*64 + lane];
    acc.x += gv.x; acc.y += gv.y;
  }
  float dv = dinv[node];
  int f0 = 2*lane, f1 = f0+1;
  float b0 = (f0<64)? bgo[f0] : bgt[f0-64];
  float b1 = (f1<64)? bgo[f1] : bgt[f1-64];
  float r0 = dv*acc.x + b0; r0 = r0>0.f? r0 : 0.f;
  float r1 = dv*acc.y + b1; r1 = r1>0.f? r1 : 0.f;
  float2 st; st.x=r0; st.y=r1;
  reinterpret_cast<float2*>(r)[(size_t)node*64 + lane] = st;
  float ps = r0*asrc[f0] + r1*asrc[f1];
  float pd = r0*adst[f0] + r1*adst[f1];
  #pragma unroll
  for(int m=32;m>=1;m>>=1){ ps += __shfl_xor(ps,m,64); pd += __shfl_xor(pd,m,64); }
  if(lane==0){ ssc[node]=ps; dsc[node]=pd; }
}

// ----------------------- masked attention pull -----------------------------
__global__ __launch_bounds__(256) void k_attn(const float* __restrict__ r,
    const int* __restrict__ offs, const int* __restrict__ cnt, const int* __restrict__ csr,
    const float* __restrict__ tmask, const float* __restrict__ ssc, const float* __restrict__ dsc,
    float* __restrict__ h, int n){
  int wv = __builtin_amdgcn_readfirstlane((int)threadIdx.x >> 6);
  int lane = threadIdx.x & 63;
  int node = blockIdx.x*4 + wv;
  if(node>=n) return;
  int off = offs[node];
  int dc  = cnt[node];
  float dscv = dsc[node];
  float lmax = -3.4e38f;
  for(int i=lane;i<dc;i+=64){
    int u = csr[off+i];
    if(tmask[u] > 0.f){
      float e = lrelu(ssc[u] + dscv);
      lmax = fmaxf(lmax, e);
    }
  }
  #pragma unroll
  for(int m=32;m>=1;m>>=1) lmax = fmaxf(lmax, __shfl_xor(lmax,m,64));
  float denom = 0.f, num = 0.f;
  if(lmax > -3.0e38f){            // at least one treated in-edge
    for(int i=0;i<dc;i++){
      int u = csr[off+i];         // wave-uniform
      float tm = tmask[u];        // wave-uniform
      if(tm > 0.f){
        float e = lrelu(ssc[u] + dscv);
        float w = __expf(e - lmax);
        denom += w;
        num += w * r[(size_t)u*128 + 64 + lane];   // r_t[u][lane]
      }
    }
  }
  h[(size_t)node*64 + lane] = num/(denom + 1e-16f);
}

// ------------------------------ heads --------------------------------------
// Block = 256 thr = 64 nodes x 4 output-chunks. Thread owns acc[16] (VGPRs).
// Activations ping-pong A<->B in LDS ([64][65] pad). Chunk id c is
// readfirstlane'd -> weight/bias addresses provably wave-uniform -> s_load.
__global__ __launch_bounds__(256) void k_heads(
    const float* __restrict__ r, const float* __restrict__ h, const int* __restrict__ t,
    const float* __restrict__ Wenc, const float* __restrict__ benc,
    const float* __restrict__ dw1, const float* __restrict__ db1,
    const float* __restrict__ dw2, const float* __restrict__ db2,
    const float* __restrict__ dw3, const float* __restrict__ db3,
    const float* __restrict__ p1w1, const float* __restrict__ p1b1,
    const float* __restrict__ p1w2, const float* __restrict__ p1b2,
    const float* __restrict__ p1w3, const float* __restrict__ p1b3,
    const float* __restrict__ p0w1, const float* __restrict__ p0b1,
    const float* __restrict__ p0w2, const float* __restrict__ p0b2,
    const float* __restrict__ p0w3, const float* __restrict__ p0b3,
    float* __restrict__ out, int nTot){
  __shared__ float A[64][65];
  __shared__ float B[64][65];
  int tid = threadIdx.x;
  int n   = tid & 63;                                        // node within block
  int c   = __builtin_amdgcn_readfirstlane(tid >> 6);        // chunk (wave-uniform!)
  int node = blockIdx.x*64 + n;
  bool act = node < nTot;

  // stage 64 nodes x 64 feats: dst[f][nn] = src[gn*stride + f]
  auto stage = [&](float (*dst)[65], const float* __restrict__ src, int stride){
    __syncthreads();
    #pragma unroll 1
    for(int it=0; it<16; it++){
      int e  = it*256 + tid;
      int nn = e >> 6, f = e & 63;
      int gn = blockIdx.x*64 + nn;
      dst[f][nn] = (gn < nTot) ? src[(size_t)gn*stride + f] : 0.f;
    }
    __syncthreads();
  };

  // layer: outb = lrelu?(in @ w + b), chunk c of outputs per thread
  auto mlayer = [&](float (*in)[65], float (*outb)[65],
                    const float* __restrict__ w, const float* __restrict__ b, bool relu){
    float acc[16];
    #pragma unroll
    for(int i=0;i<16;i++) acc[i] = b[c*16+i];
    #pragma unroll 1
    for(int k=0;k<64;k++){
      float ink = in[k][n];
      #pragma unroll
      for(int i=0;i<16;i++) acc[i] += ink * w[k*64 + c*16 + i];
    }
    #pragma unroll
    for(int i=0;i<16;i++) outb[c*16+i][n] = relu ? lrelu(acc[i]) : acc[i];
    __syncthreads();
  };

  auto last = [&](float (*in)[65], const float* __restrict__ w3, float b3)->float{
    float o = b3;
    #pragma unroll 1
    for(int k=0;k<64;k++) o += in[k][n]*w3[k];
    return o;
  };

  // ---- discriminator on r_t ----
  stage(A, r + 64, 128);
  mlayer(A, B, dw1, db1, true);
  mlayer(B, A, dw2, db2, true);
  float od = last(A, dw3, db3[0]);
  if(act && c==0) out[node] = 1.f/(1.f + __expf(-od));

  // ---- encoder: reps = [r_o | h] @ Wenc + benc ----
  float rep[16];
  #pragma unroll
  for(int i=0;i<16;i++) rep[i] = benc[c*16+i];
  stage(A, r, 128);                       // r_o
  #pragma unroll 1
  for(int k=0;k<64;k++){
    float ink = A[k][n];
    #pragma unroll
    for(int i=0;i<16;i++) rep[i] += ink * Wenc[k*64 + c*16 + i];
  }
  stage(A, h, 64);                        // h
  #pragma unroll 1
  for(int k=0;k<64;k++){
    float ink = A[k][n];
    #pragma unroll
    for(int i=0;i<16;i++) rep[i] += ink * Wenc[(64+k)*64 + c*16 + i];
  }
  __syncthreads();                        // A reads done before B write barrier below
  #pragma unroll
  for(int i=0;i<16;i++) B[c*16+i][n] = rep[i];
  __syncthreads();
  // coalesced reps -> global via B
  #pragma unroll 1
  for(int it=0; it<16; it++){
    int e  = it*256 + tid;
    int nn = e >> 6, f = e & 63;
    int gn = blockIdx.x*64 + nn;
    if(gn < nTot) out[(size_t)2*nTot + (size_t)gn*64 + f] = B[f][nn];
  }

  // ---- predictor 1 (destroys B) ----
  mlayer(B, A, p1w1, p1b1, true);
  mlayer(A, B, p1w2, p1b2, true);
  float o1 = last(B, p1w3, p1b3[0]);
  // restore reps into B from registers
  __syncthreads();
  #pragma unroll
  for(int i=0;i<16;i++) B[c*16+i][n] = rep[i];
  __syncthreads();
  // ---- predictor 0 ----
  mlayer(B, A, p0w1, p0b1, true);
  mlayer(A, B, p0w2, p0b2, true);
  float o0 = last(B, p0w3, p0b3[0]);
  if(act && c==0) out[nTot + node] = (t[node] > 0) ? o1 : o0;
}

// ------------------------------ launch -------------------------------------
extern "C" void kernel_launch(void* const* d_in, const int* in_sizes, int n_in,
                              void* d_out, int out_size, void* d_ws, size_t ws_size,
                              hipStream_t stream){
  const float* x   = (const float*)d_in[0];
  const int*   t   = (const int*)d_in[1];
  const int*   ei  = (const int*)d_in[3];   // int32 (JAX x64 off); sniff handles int64
  const float* Wgo = (const float*)d_in[4];  const float* bgo = (const float*)d_in[5];
  const float* Wgt = (const float*)d_in[6];  const float* bgt = (const float*)d_in[7];
  const float* asrc= (const float*)d_in[8];  const float* adst= (const float*)d_in[9];
  const float* Wenc= (const float*)d_in[10]; const float* benc= (const float*)d_in[11];
  const float* dw1 = (const float*)d_in[12]; const float* db1 = (const float*)d_in[13];
  const float* dw2 = (const float*)d_in[14]; const float* db2 = (const float*)d_in[15];
  const float* dw3 = (const float*)d_in[16]; const float* db3 = (const float*)d_in[17];
  const float* p1w1= (const float*)d_in[18]; const float* p1b1= (const float*)d_in[19];
  const float* p1w2= (const float*)d_in[20]; const float* p1b2= (const float*)d_in[21];
  const float* p1w3= (const float*)d_in[22]; const float* p1b3= (const float*)d_in[23];
  const float* p0w1= (const float*)d_in[24]; const float* p0b1= (const float*)d_in[25];
  const float* p0w2= (const float*)d_in[26]; const float* p0b2= (const float*)d_in[27];
  const float* p0w3= (const float*)d_in[28]; const float* p0b3= (const float*)d_in[29];
  float* out = (float*)d_out;

  int N = in_sizes[0]/128;
  int E = in_sizes[3]/2;

  char* wp = (char*)d_ws;
  auto alloc = [&](size_t bytes)->void*{
    void* p = (void*)wp; wp += (bytes + 255) & ~(size_t)255; return p;
  };
  float* g     = (float*)alloc((size_t)N*128*sizeof(float));
  float* r     = (float*)alloc((size_t)N*128*sizeof(float));
  int*   csr   = (int*)  alloc((size_t)E*sizeof(int));
  int*   offs  = (int*)  alloc((size_t)N*sizeof(int));
  int*   cursor= (int*)  alloc((size_t)N*sizeof(int));
  int*   cnt   = (int*)  alloc((size_t)N*sizeof(int));
  float* dinv  = (float*)alloc((size_t)N*sizeof(float));
  float* tmask = (float*)alloc((size_t)N*sizeof(float));
  float* ssc   = (float*)alloc((size_t)N*sizeof(float));
  float* dsc   = (float*)alloc((size_t)N*sizeof(float));
  int*   parts = (int*)  alloc(4096);
  int*   flag  = (int*)  alloc(256);
  float* h     = g;                  // g is dead after k_gcn; reuse for h

  int nbN  = (N+255)/256;
  int nbE  = (E+255)/256;
  int nbSc = (N+2047)/2048;

  k_sniff   <<<1,   256, 0, stream>>>(ei, flag, 1024);
  k_zero    <<<nbN, 256, 0, stream>>>(cnt, N);
  k_count   <<<nbE, 256, 0, stream>>>(ei, flag, cnt, E, N);
  k_nodeprep<<<nbN, 256, 0, stream>>>(cnt, t, dinv, tmask, N);
  k_scan1   <<<nbSc,256, 0, stream>>>(cnt, offs, parts, N);
  k_scan2   <<<1,   64,  0, stream>>>(parts, nbSc);
  k_scan3   <<<nbN, 256, 0, stream>>>(offs, parts, cursor, N);
  k_scatter <<<nbE, 256, 0, stream>>>(ei, flag, cursor, csr, E, N);
  k_transform<<<(N+255)/256, 256, 0, stream>>>(x, Wgo, Wgt, dinv, g, N);
  k_gcn     <<<(N+3)/4, 256, 0, stream>>>(g, offs, cnt, csr, dinv, bgo, bgt,
                                          asrc, adst, r, ssc, dsc, N);
  k_attn    <<<(N+3)/4, 256, 0, stream>>>(r, offs, cnt, csr, tmask, ssc, dsc, h, N);
  k_heads   <<<(N+63)/64, 256, 0, stream>>>(r, h, t,
              Wenc, benc, dw1, db1, dw2, db2, dw3, db3,
              p1w1, p1b1, p1w2, p1b2, p1w3, p1b3,
              p0w1, p0b1, p0w2, p0b2, p0w3, p0b3, out, N);
}

// Round 12
// 874.600 us; speedup vs baseline: 1.6821x; 1.1981x over previous
//
#include <hip/hip_runtime.h>
#include <math.h>

// SPNet: GCN(x@Wgo), GCN(x@Wgt) -> masked attention -> encoder -> MLP heads.
// CSR-by-dst build (counts -> scan -> scatter), then all segment ops are
// deterministic per-node pulls. edge_index arrives as int32 (JAX x64 off);
// a device-side sniff also tolerates true int64 (reads low words).
// R8: k_heads restructured (thread = node x 16-output chunk) -> no scratch.
// R9: chunk id via readfirstlane -> weight loads become s_load.
// R10: drop the '#pragma unroll 1' serialization in k_heads (s_load latency
//      was exposed per-k: VALUBusy 17%, 343 us). unroll 4/8 -> loads overlap.

__device__ __forceinline__ float lrelu(float v){ return v >= 0.f ? v : 0.2f*v; }

__device__ __forceinline__ int edge_at(const int* __restrict__ ei, int w64, size_t idx){
  return w64 ? ei[2*idx] : ei[idx];     // int64 little-endian: low word at 2*idx
}

// ----------------------------- graph build --------------------------------
__global__ void k_sniff(const int* __restrict__ ei, int* __restrict__ flag, int m){
  __shared__ int s;
  if(threadIdx.x==0) s = 0;
  __syncthreads();
  int acc = 0;
  for(int i=threadIdx.x; i<m; i+=blockDim.x) acc |= ei[2*i+1];
  atomicOr(&s, acc);
  __syncthreads();
  if(threadIdx.x==0) flag[0] = (s==0) ? 1 : 0;   // all odd words zero -> int64
}

__global__ void k_zero(int* __restrict__ p, int n){
  int i = blockIdx.x*blockDim.x + threadIdx.x;
  if(i<n) p[i]=0;
}

__global__ void k_count(const int* __restrict__ ei, const int* __restrict__ flag,
                        int* __restrict__ cnt, int E, int n){
  int e = blockIdx.x*blockDim.x + threadIdx.x;
  if(e<E){
    int d = edge_at(ei, flag[0], (size_t)E + e);
    d = min(max(d,0), n-1);                      // insurance: no OOB write
    atomicAdd(&cnt[d],1);
  }
}

__global__ void k_nodeprep(const int* __restrict__ cnt, const int* __restrict__ t,
                           float* __restrict__ dinv, float* __restrict__ tmask, int n){
  int i = blockIdx.x*blockDim.x + threadIdx.x;
  if(i<n){
    dinv[i] = rsqrtf((float)(cnt[i]+1));   // deg = in-degree + self-loop >= 1
    tmask[i] = (t[i] > 0) ? 1.f : 0.f;
  }
}

// block scans 2048 elems (256 thr x 8); writes block-local exclusive + partial
__global__ void k_scan1(const int* __restrict__ cnt, int* __restrict__ offs,
                        int* __restrict__ partials, int n){
  __shared__ int s[256];
  int tid = threadIdx.x;
  int base = blockIdx.x*2048 + tid*8;
  int v[8]; int sum=0;
  #pragma unroll
  for(int j=0;j<8;j++){ int idx=base+j; v[j] = (idx<n)? cnt[idx] : 0; sum += v[j]; }
  s[tid]=sum; __syncthreads();
  for(int off=1;off<256;off<<=1){
    int tv = (tid>=off)? s[tid-off] : 0;
    __syncthreads();
    s[tid] += tv;
    __syncthreads();
  }
  if(tid==255) partials[blockIdx.x] = s[255];
  int run = s[tid]-sum;
  #pragma unroll
  for(int j=0;j<8;j++){ int idx=base+j; if(idx<n) offs[idx]=run; run += v[j]; }
}

__global__ void k_scan2(int* __restrict__ partials, int nb){
  int lane = threadIdx.x;
  int v = (lane<nb)? partials[lane] : 0;
  int inc = v;
  for(int off=1;off<64;off<<=1){ int t2 = __shfl_up(inc,off,64); if(lane>=off) inc += t2; }
  if(lane<nb) partials[lane] = inc - v;     // exclusive
}

__global__ void k_scan3(int* __restrict__ offs, const int* __restrict__ partials,
                        int* __restrict__ cursor, int n){
  int i = blockIdx.x*blockDim.x + threadIdx.x;
  if(i<n){ int o = offs[i] + partials[i>>11]; offs[i]=o; cursor[i]=o; }
}

__global__ void k_scatter(const int* __restrict__ ei, const int* __restrict__ flag,
                          int* __restrict__ cursor, int* __restrict__ csr, int E, int n){
  int e = blockIdx.x*blockDim.x + threadIdx.x;
  if(e<E){
    int w64 = flag[0];
    int s = edge_at(ei, w64, (size_t)e);
    int d = edge_at(ei, w64, (size_t)E + e);
    s = min(max(s,0), n-1);
    d = min(max(d,0), n-1);
    int pos = atomicAdd(&cursor[d], 1);
    csr[pos] = s;
  }
}

// --------------------- transform: g = dinv * (x @ [Wgo|Wgt]) ---------------
// lanes = rows; x row in 128 VGPRs; W via wave-uniform scalar loads.
__global__ __launch_bounds__(256) void k_transform(const float* __restrict__ x,
    const float* __restrict__ Wgo, const float* __restrict__ Wgt,
    const float* __restrict__ dinv, float* __restrict__ g, int n){
  int wv = __builtin_amdgcn_readfirstlane((int)threadIdx.x >> 6);
  int lane = threadIdx.x & 63;
  int row = blockIdx.x*256 + wv*64 + lane;
  bool ok = row < n;
  int rowc = ok ? row : (n-1);
  const float4* xp = reinterpret_cast<const float4*>(x) + (size_t)rowc*32;
  float xr[128];
  #pragma unroll
  for(int q=0;q<32;q++){
    float4 t4 = xp[q];
    xr[4*q]=t4.x; xr[4*q+1]=t4.y; xr[4*q+2]=t4.z; xr[4*q+3]=t4.w;
  }
  float dv = dinv[rowc];
  float* grow = g + (size_t)rowc*128;
  #pragma unroll 1
  for(int c=0;c<64;c++){
    float a0=0.f,a1=0.f,a2=0.f,a3=0.f;
    #pragma unroll
    for(int k=0;k<128;k+=4){
      a0 += xr[k+0]*Wgo[(k+0)*64+c];
      a1 += xr[k+1]*Wgo[(k+1)*64+c];
      a2 += xr[k+2]*Wgo[(k+2)*64+c];
      a3 += xr[k+3]*Wgo[(k+3)*64+c];
    }
    if(ok) grow[c] = dv*((a0+a1)+(a2+a3));
  }
  #pragma unroll 1
  for(int c=0;c<64;c++){
    float a0=0.f,a1=0.f,a2=0.f,a3=0.f;
    #pragma unroll
    for(int k=0;k<128;k+=4){
      a0 += xr[k+0]*Wgt[(k+0)*64+c];
      a1 += xr[k+1]*Wgt[(k+1)*64+c];
      a2 += xr[k+2]*Wgt[(k+2)*64+c];
      a3 += xr[k+3]*Wgt[(k+3)*64+c];
    }
    if(ok) grow[64+c] = dv*((a0+a1)+(a2+a3));
  }
}

// ---------------- GCN pull + bias/relu + attention scores ------------------
// one wave per node; lane handles features (2*lane, 2*lane+1) of the 128.
__global__ __launch_bounds__(256) void k_gcn(const float* __restrict__ g,
    const int* __restrict__ offs, const int* __restrict__ cnt, const int* __restrict__ csr,
    const float* __restrict__ dinv, const float* __restrict__ bgo, const float* __restrict__ bgt,
    const float* __restrict__ asrc, const float* __restrict__ adst,
    float* __restrict__ r, float* __restrict__ ssc, float* __restrict__ dsc, int n){
  int wv = __builtin_amdgcn_readfirstlane((int)threadIdx.x >> 6);
  int lane = threadIdx.x & 63;
  int node = blockIdx.x*4 + wv;
  if(node>=n) return;
  const float2* gt = reinterpret_cast<const float2*>(g);
  int off = offs[node];
  int dc  = cnt[node];
  float2 acc = gt[(size_t)node*64 + lane];      // self loop
  for(int i=0;i<dc;i++){
    int u = csr[off+i];                         // wave-uniform -> scalar load
    float2 gv = gt[(size_t)u*64 + lane];
    acc.x += gv.x; acc.y += gv.y;
  }
  float dv = dinv[node];
  int f0 = 2*lane, f1 = f0+1;
  float b0 = (f0<64)? bgo[f0] : bgt[f0-64];
  float b1 = (f1<64)? bgo[f1] : bgt[f1-64];
  float r0 = dv*acc.x + b0; r0 = r0>0.f? r0 : 0.f;
  float r1 = dv*acc.y + b1; r1 = r1>0.f? r1 : 0.f;
  float2 st; st.x=r0; st.y=r1;
  reinterpret_cast<float2*>(r)[(size_t)node*64 + lane] = st;
  float ps = r0*asrc[f0] + r1*asrc[f1];
  float pd = r0*adst[f0] + r1*adst[f1];
  #pragma unroll
  for(int m=32;m>=1;m>>=1){ ps += __shfl_xor(ps,m,64); pd += __shfl_xor(pd,m,64); }
  if(lane==0){ ssc[node]=ps; dsc[node]=pd; }
}

// ----------------------- masked attention pull -----------------------------
__global__ __launch_bounds__(256) void k_attn(const float* __restrict__ r,
    const int* __restrict__ offs, const int* __restrict__ cnt, const int* __restrict__ csr,
    const float* __restrict__ tmask, const float* __restrict__ ssc, const float* __restrict__ dsc,
    float* __restrict__ h, int n){
  int wv = __builtin_amdgcn_readfirstlane((int)threadIdx.x >> 6);
  int lane = threadIdx.x & 63;
  int node = blockIdx.x*4 + wv;
  if(node>=n) return;
  int off = offs[node];
  int dc  = cnt[node];
  float dscv = dsc[node];
  float lmax = -3.4e38f;
  for(int i=lane;i<dc;i+=64){
    int u = csr[off+i];
    if(tmask[u] > 0.f){
      float e = lrelu(ssc[u] + dscv);
      lmax = fmaxf(lmax, e);
    }
  }
  #pragma unroll
  for(int m=32;m>=1;m>>=1) lmax = fmaxf(lmax, __shfl_xor(lmax,m,64));
  float denom = 0.f, num = 0.f;
  if(lmax > -3.0e38f){            // at least one treated in-edge
    for(int i=0;i<dc;i++){
      int u = csr[off+i];         // wave-uniform
      float tm = tmask[u];        // wave-uniform
      if(tm > 0.f){
        float e = lrelu(ssc[u] + dscv);
        float w = __expf(e - lmax);
        denom += w;
        num += w * r[(size_t)u*128 + 64 + lane];   // r_t[u][lane]
      }
    }
  }
  h[(size_t)node*64 + lane] = num/(denom + 1e-16f);
}

// ------------------------------ heads --------------------------------------
// Block = 256 thr = 64 nodes x 4 output-chunks. Thread owns acc[16] (VGPRs).
// Activations ping-pong A<->B in LDS ([64][65] pad). Chunk id c is
// readfirstlane'd -> weight loads are s_load; k-loops unrolled 4 so several
// s_load_dwordx16 are in flight (R10: unroll 1 exposed full s_load latency).
__global__ __launch_bounds__(256) void k_heads(
    const float* __restrict__ r, const float* __restrict__ h, const int* __restrict__ t,
    const float* __restrict__ Wenc, const float* __restrict__ benc,
    const float* __restrict__ dw1, const float* __restrict__ db1,
    const float* __restrict__ dw2, const float* __restrict__ db2,
    const float* __restrict__ dw3, const float* __restrict__ db3,
    const float* __restrict__ p1w1, const float* __restrict__ p1b1,
    const float* __restrict__ p1w2, const float* __restrict__ p1b2,
    const float* __restrict__ p1w3, const float* __restrict__ p1b3,
    const float* __restrict__ p0w1, const float* __restrict__ p0b1,
    const float* __restrict__ p0w2, const float* __restrict__ p0b2,
    const float* __restrict__ p0w3, const float* __restrict__ p0b3,
    float* __restrict__ out, int nTot){
  __shared__ float A[64][65];
  __shared__ float B[64][65];
  int tid = threadIdx.x;
  int n   = tid & 63;                                        // node within block
  int c   = __builtin_amdgcn_readfirstlane(tid >> 6);        // chunk (wave-uniform!)
  int node = blockIdx.x*64 + n;
  bool act = node < nTot;

  // stage 64 nodes x 64 feats: dst[f][nn] = src[gn*stride + f]
  auto stage = [&](float (*dst)[65], const float* __restrict__ src, int stride){
    __syncthreads();
    #pragma unroll 4
    for(int it=0; it<16; it++){
      int e  = it*256 + tid;
      int nn = e >> 6, f = e & 63;
      int gn = blockIdx.x*64 + nn;
      dst[f][nn] = (gn < nTot) ? src[(size_t)gn*stride + f] : 0.f;
    }
    __syncthreads();
  };

  // layer: outb = lrelu?(in @ w + b), chunk c of outputs per thread
  auto mlayer = [&](float (*in)[65], float (*outb)[65],
                    const float* __restrict__ w, const float* __restrict__ b, bool relu){
    float acc[16];
    #pragma unroll
    for(int i=0;i<16;i++) acc[i] = b[c*16+i];
    #pragma unroll 4
    for(int k=0;k<64;k++){
      float ink = in[k][n];
      #pragma unroll
      for(int i=0;i<16;i++) acc[i] += ink * w[k*64 + c*16 + i];
    }
    #pragma unroll
    for(int i=0;i<16;i++) outb[c*16+i][n] = relu ? lrelu(acc[i]) : acc[i];
    __syncthreads();
  };

  auto last = [&](float (*in)[65], const float* __restrict__ w3, float b3)->float{
    float o = b3;
    #pragma unroll 8
    for(int k=0;k<64;k++) o += in[k][n]*w3[k];
    return o;
  };

  // ---- discriminator on r_t ----
  stage(A, r + 64, 128);
  mlayer(A, B, dw1, db1, true);
  mlayer(B, A, dw2, db2, true);
  float od = last(A, dw3, db3[0]);
  if(act && c==0) out[node] = 1.f/(1.f + __expf(-od));

  // ---- encoder: reps = [r_o | h] @ Wenc + benc ----
  float rep[16];
  #pragma unroll
  for(int i=0;i<16;i++) rep[i] = benc[c*16+i];
  stage(A, r, 128);                       // r_o
  #pragma unroll 4
  for(int k=0;k<64;k++){
    float ink = A[k][n];
    #pragma unroll
    for(int i=0;i<16;i++) rep[i] += ink * Wenc[k*64 + c*16 + i];
  }
  stage(A, h, 64);                        // h
  #pragma unroll 4
  for(int k=0;k<64;k++){
    float ink = A[k][n];
    #pragma unroll
    for(int i=0;i<16;i++) rep[i] += ink * Wenc[(64+k)*64 + c*16 + i];
  }
  __syncthreads();                        // A reads done before B write barrier below
  #pragma unroll
  for(int i=0;i<16;i++) B[c*16+i][n] = rep[i];
  __syncthreads();
  // coalesced reps -> global via B
  #pragma unroll 4
  for(int it=0; it<16; it++){
    int e  = it*256 + tid;
    int nn = e >> 6, f = e & 63;
    int gn = blockIdx.x*64 + nn;
    if(gn < nTot) out[(size_t)2*nTot + (size_t)gn*64 + f] = B[f][nn];
  }

  // ---- predictor 1 (destroys B) ----
  mlayer(B, A, p1w1, p1b1, true);
  mlayer(A, B, p1w2, p1b2, true);
  float o1 = last(B, p1w3, p1b3[0]);
  // restore reps into B from registers
  __syncthreads();
  #pragma unroll
  for(int i=0;i<16;i++) B[c*16+i][n] = rep[i];
  __syncthreads();
  // ---- predictor 0 ----
  mlayer(B, A, p0w1, p0b1, true);
  mlayer(A, B, p0w2, p0b2, true);
  float o0 = last(B, p0w3, p0b3[0]);
  if(act && c==0) out[nTot + node] = (t[node] > 0) ? o1 : o0;
}

// ------------------------------ launch -------------------------------------
extern "C" void kernel_launch(void* const* d_in, const int* in_sizes, int n_in,
                              void* d_out, int out_size, void* d_ws, size_t ws_size,
                              hipStream_t stream){
  const float* x   = (const float*)d_in[0];
  const int*   t   = (const int*)d_in[1];
  const int*   ei  = (const int*)d_in[3];   // int32 (JAX x64 off); sniff handles int64
  const float* Wgo = (const float*)d_in[4];  const float* bgo = (const float*)d_in[5];
  const float* Wgt = (const float*)d_in[6];  const float* bgt = (const float*)d_in[7];
  const float* asrc= (const float*)d_in[8];  const float* adst= (const float*)d_in[9];
  const float* Wenc= (const float*)d_in[10]; const float* benc= (const float*)d_in[11];
  const float* dw1 = (const float*)d_in[12]; const float* db1 = (const float*)d_in[13];
  const float* dw2 = (const float*)d_in[14]; const float* db2 = (const float*)d_in[15];
  const float* dw3 = (const float*)d_in[16]; const float* db3 = (const float*)d_in[17];
  const float* p1w1= (const float*)d_in[18]; const float* p1b1= (const float*)d_in[19];
  const float* p1w2= (const float*)d_in[20]; const float* p1b2= (const float*)d_in[21];
  const float* p1w3= (const float*)d_in[22]; const float* p1b3= (const float*)d_in[23];
  const float* p0w1= (const float*)d_in[24]; const float* p0b1= (const float*)d_in[25];
  const float* p0w2= (const float*)d_in[26]; const float* p0b2= (const float*)d_in[27];
  const float* p0w3= (const float*)d_in[28]; const float* p0b3= (const float*)d_in[29];
  float* out = (float*)d_out;

  int N = in_sizes[0]/128;
  int E = in_sizes[3]/2;

  char* wp = (char*)d_ws;
  auto alloc = [&](size_t bytes)->void*{
    void* p = (void*)wp; wp += (bytes + 255) & ~(size_t)255; return p;
  };
  float* g     = (float*)alloc((size_t)N*128*sizeof(float));
  float* r     = (float*)alloc((size_t)N*128*sizeof(float));
  int*   csr   = (int*)  alloc((size_t)E*sizeof(int));
  int*   offs  = (int*)  alloc((size_t)N*sizeof(int));
  int*   cursor= (int*)  alloc((size_t)N*sizeof(int));
  int*   cnt   = (int*)  alloc((size_t)N*sizeof(int));
  float* dinv  = (float*)alloc((size_t)N*sizeof(float));
  float* tmask = (float*)alloc((size_t)N*sizeof(float));
  float* ssc   = (float*)alloc((size_t)N*sizeof(float));
  float* dsc   = (float*)alloc((size_t)N*sizeof(float));
  int*   parts = (int*)  alloc(4096);
  int*   flag  = (int*)  alloc(256);
  float* h     = g;                  // g is dead after k_gcn; reuse for h

  int nbN  = (N+255)/256;
  int nbE  = (E+255)/256;
  int nbSc = (N+2047)/2048;

  k_sniff   <<<1,   256, 0, stream>>>(ei, flag, 1024);
  k_zero    <<<nbN, 256, 0, stream>>>(cnt, N);
  k_count   <<<nbE, 256, 0, stream>>>(ei, flag, cnt, E, N);
  k_nodeprep<<<nbN, 256, 0, stream>>>(cnt, t, dinv, tmask, N);
  k_scan1   <<<nbSc,256, 0, stream>>>(cnt, offs, parts, N);
  k_scan2   <<<1,   64,  0, stream>>>(parts, nbSc);
  k_scan3   <<<nbN, 256, 0, stream>>>(offs, parts, cursor, N);
  k_scatter <<<nbE, 256, 0, stream>>>(ei, flag, cursor, csr, E, N);
  k_transform<<<(N+255)/256, 256, 0, stream>>>(x, Wgo, Wgt, dinv, g, N);
  k_gcn     <<<(N+3)/4, 256, 0, stream>>>(g, offs, cnt, csr, dinv, bgo, bgt,
                                          asrc, adst, r, ssc, dsc, N);
  k_attn    <<<(N+3)/4, 256, 0, stream>>>(r, offs, cnt, csr, tmask, ssc, dsc, h, N);
  k_heads   <<<(N+63)/64, 256, 0, stream>>>(r, h, t,
              Wenc, benc, dw1, db1, dw2, db2, dw3, db3,
              p1w1, p1b1, p1w2, p1b2, p1w3, p1b3,
              p0w1, p0b1, p0w2, p0b2, p0w3, p0b3, out, N);
}